// Round 3
// baseline (203.753 us; speedup 1.0000x reference)
//
#include <hip/hip_runtime.h>
#include <hip/hip_bf16.h>
#include <stdint.h>

// out = x @ Wc^T + bc, where Wc = sum_k w_k * W[ids_k] (1024x1024), x:[4096][1024].
// prep: build Wc (bf16) + bc, convert x -> bf16 (unrolled K=8 gather, 2 float4/thread).
// gemm: 64x128 tile, BK=64, 512 blocks (2/CU), XOR-swizzled LDS, double-buffered
//       (single barrier per K-iter, DMA in flight across the whole compute phase).

typedef __attribute__((ext_vector_type(8))) short short8;
typedef __attribute__((ext_vector_type(4))) float float4v;

#define DIMK 1024
#define DIMN 1024
#define DIMM 4096

__device__ __forceinline__ unsigned short f2bf_rtn(float f) {
  union { float f; unsigned u; } v; v.f = f;
  unsigned u = v.u;
  return (unsigned short)((u + 0x7fffu + ((u >> 16) & 1u)) >> 16);
}

// blocks [0,1024): build Wc (bf16) + bc; blocks [1024,3072): convert x -> bf16
__global__ __launch_bounds__(256) void prep_kernel(
    const float* __restrict__ x, const float* __restrict__ W,
    const float* __restrict__ bia, const int* __restrict__ ids,
    const float* __restrict__ wts,
    unsigned short* __restrict__ xb, unsigned short* __restrict__ Wc,
    float* __restrict__ bc, int K)
{
  const int bid = blockIdx.x;
  if (bid < 1024) {
    // preload ids/weights into registers (K==8 in practice; guard stays general)
    int   id[8];
    float wv[8];
#pragma unroll
    for (int k = 0; k < 8; ++k) {
      id[k] = (k < K) ? ids[k] : 0;
      wv[k] = (k < K) ? wts[k] : 0.f;
    }
    const int t  = bid * 256 + threadIdx.x;   // float4 groups of Wc
    const int o  = t >> 8;
    const int d4 = (t & 255) << 2;
    float ax = 0.f, ay = 0.f, az = 0.f, aw = 0.f;
#pragma unroll
    for (int k = 0; k < 8; ++k) {
      const float4 w4 = *reinterpret_cast<const float4*>(
          &W[((size_t)id[k] << 20) + ((size_t)o << 10) + d4]);
      ax += wv[k] * w4.x; ay += wv[k] * w4.y; az += wv[k] * w4.z; aw += wv[k] * w4.w;
    }
    ushort4 r;
    r.x = f2bf_rtn(ax); r.y = f2bf_rtn(ay); r.z = f2bf_rtn(az); r.w = f2bf_rtn(aw);
    *reinterpret_cast<ushort4*>(&Wc[(size_t)t << 2]) = r;
    if (t < DIMN) {
      float s = 0.f;
#pragma unroll
      for (int k = 0; k < 8; ++k) s += wv[k] * bia[id[k] * DIMN + t];
      bc[t] = s;
    }
  } else {
    // x -> bf16: 2 float4 groups per thread, both coalesced
    const size_t t0 = (size_t)(bid - 1024) * 512 + threadIdx.x;
    const float4 v0 = *reinterpret_cast<const float4*>(&x[t0 << 2]);
    const float4 v1 = *reinterpret_cast<const float4*>(&x[(t0 + 256) << 2]);
    ushort4 r0, r1;
    r0.x = f2bf_rtn(v0.x); r0.y = f2bf_rtn(v0.y); r0.z = f2bf_rtn(v0.z); r0.w = f2bf_rtn(v0.w);
    r1.x = f2bf_rtn(v1.x); r1.y = f2bf_rtn(v1.y); r1.z = f2bf_rtn(v1.z); r1.w = f2bf_rtn(v1.w);
    *reinterpret_cast<ushort4*>(&xb[t0 << 2]) = r0;
    *reinterpret_cast<ushort4*>(&xb[(t0 + 256) << 2]) = r1;
  }
}

__device__ __forceinline__ void load_lds16(const void* g, void* l) {
  __builtin_amdgcn_global_load_lds(
      (const __attribute__((address_space(1))) void*)g,
      (__attribute__((address_space(3))) void*)l, 16, 0, 0);
}

// Tile 64(M) x 128(N), BK=64, double-buffered. 4 waves, wave tile 32x64 (2x4 MFMA).
// LDS XOR swizzle: row r, global 16B-group g at phys group g^(r&7).
// Staging chunk = 8 rows x 64 cols: lane l -> row l>>3, phys group l&7,
// source col group = (l&7)^(l>>3). ds_read phys group (s*4+quad)^(r16&7):
// 2 lanes/bank = free (m136).
__global__ __launch_bounds__(256, 2) void gemm_kernel(
    const unsigned short* __restrict__ xb,   // [4096][1024] bf16
    const unsigned short* __restrict__ Wc,   // [1024][1024] bf16 (row=n)
    const float* __restrict__ bc,            // [1024]
    float* __restrict__ out)                 // [4096][1024] fp32
{
  constexpr int BK = 64;
  __shared__ __align__(16) unsigned short As[2][64 * BK];    // 2 x 8 KB
  __shared__ __align__(16) unsigned short Bs[2][128 * BK];   // 2 x 16 KB

  const int tid  = threadIdx.x;
  const int wave = tid >> 6;
  const int lane = tid & 63;
  const int m0 = blockIdx.y * 64;
  const int n0 = blockIdx.x * 128;

  // staging: wave w -> A rows [w*16, +16) (2 chunks), B rows [w*32, +32) (4 chunks)
  const int srow = lane >> 3;
  const int scol = (((lane & 7) ^ srow) << 3);
  const unsigned short* gA0 = xb + (size_t)(m0 + wave * 16 + srow) * DIMK + scol;
  const unsigned short* gB0 = Wc + (size_t)(n0 + wave * 32 + srow) * DIMK + scol;
  const int aoff = wave * 16 * BK;
  const int boff = wave * 32 * BK;

  const int wm   = (wave >> 1) * 32;
  const int wn   = (wave & 1) * 64;
  const int quad = lane >> 4;
  const int r16  = lane & 15;
  const int rx   = r16 & 7;
  const int po0  = ((quad ^ rx) << 3);        // kstep 0 phys group offset (elems)
  const int po1  = (((4 + quad) ^ rx) << 3);  // kstep 1

  const float4v zero = {0.f, 0.f, 0.f, 0.f};
  float4v acc[2][4];
#pragma unroll
  for (int i = 0; i < 2; ++i)
#pragma unroll
    for (int j = 0; j < 4; ++j) acc[i][j] = zero;

  auto issue = [&](int buf, int k0) {
    load_lds16(gA0 + k0,            &As[buf][aoff]);
    load_lds16(gA0 + k0 + 8 * DIMK, &As[buf][aoff + 8 * BK]);
    load_lds16(gB0 + k0,            &Bs[buf][boff]);
    load_lds16(gB0 + k0 + 8 * DIMK, &Bs[buf][boff + 8 * BK]);
    load_lds16(gB0 + k0 + 16 * DIMK, &Bs[buf][boff + 16 * BK]);
    load_lds16(gB0 + k0 + 24 * DIMK, &Bs[buf][boff + 24 * BK]);
  };

  auto compute = [&](int buf) {
#pragma unroll
    for (int s = 0; s < 2; ++s) {
      const int po = s ? po1 : po0;
      short8 af[2], bf[4];
#pragma unroll
      for (int mt = 0; mt < 2; ++mt)
        af[mt] = *reinterpret_cast<const short8*>(&As[buf][(wm + mt * 16 + r16) * BK + po]);
#pragma unroll
      for (int nt = 0; nt < 4; ++nt)
        bf[nt] = *reinterpret_cast<const short8*>(&Bs[buf][(wn + nt * 16 + r16) * BK + po]);
#pragma unroll
      for (int mt = 0; mt < 2; ++mt)
#pragma unroll
        for (int nt = 0; nt < 4; ++nt)
          acc[mt][nt] = __builtin_amdgcn_mfma_f32_16x16x32_bf16(af[mt], bf[nt], acc[mt][nt], 0, 0, 0);
    }
  };

  issue(0, 0);
  for (int k0 = 0; k0 < DIMK; k0 += 2 * BK) {
    __syncthreads();                     // buf0 DMA done; prior reads of buf1 done
    if (k0 + BK < DIMK) issue(1, k0 + BK);
    compute(0);
    __syncthreads();                     // buf1 DMA done; this iter's reads of buf0 done
    if (k0 + 2 * BK < DIMK) issue(0, k0 + 2 * BK);
    compute(1);
  }

#pragma unroll
  for (int nt = 0; nt < 4; ++nt) {
    const int col = n0 + wn + nt * 16 + r16;
    const float bias = bc[col];
#pragma unroll
    for (int mt = 0; mt < 2; ++mt) {
      const int rbase = m0 + wm + mt * 16 + quad * 4;
#pragma unroll
      for (int r = 0; r < 4; ++r)
        out[(size_t)(rbase + r) * DIMN + col] = acc[mt][nt][r] + bias;
    }
  }
}

extern "C" void kernel_launch(void* const* d_in, const int* in_sizes, int n_in,
                              void* d_out, int out_size, void* d_ws, size_t ws_size,
                              hipStream_t stream) {
  const float* x   = (const float*)d_in[0];
  const float* W   = (const float*)d_in[1];
  const float* b   = (const float*)d_in[2];
  const int*   ids = (const int*)d_in[3];
  const float* wts = (const float*)d_in[4];
  float* out = (float*)d_out;
  const int K = in_sizes[3];

  // workspace: xb 8 MB | Wc 2 MB | bc 4 KB
  unsigned short* xb = (unsigned short*)d_ws;
  unsigned short* Wc = (unsigned short*)((char*)d_ws + (8u << 20));
  float*          bc = (float*)((char*)d_ws + (10u << 20));

  prep_kernel<<<3072, 256, 0, stream>>>(x, W, b, ids, wts, xb, Wc, bc, K);
  dim3 grid(DIMN / 128, DIMM / 64);   // 8 x 64 = 512 blocks, 2/CU
  gemm_kernel<<<grid, 256, 0, stream>>>(xb, Wc, bc, out);
}